// Round 7
// baseline (479.425 us; speedup 1.0000x reference)
//
#include <hip/hip_runtime.h>

#define NC 512   // N_CLUSTERS

// ===========================================================================
// Pre-pass: dstT[w][s] = (u16)src[s][w]  (transpose verified R3/R5/R6).
// Merged: blocks 0..63 transpose conv_lut, 64..127 fc_lut.
// ===========================================================================
__global__ __launch_bounds__(256) void k_transpose_pack2(
    const int* __restrict__ srcA, unsigned short* __restrict__ dstA,
    const int* __restrict__ srcB, unsigned short* __restrict__ dstB)
{
    __shared__ unsigned short tile[64][65];
    int bid = blockIdx.x & 63;
    const int* src = (blockIdx.x < 64) ? srcA : srcB;
    unsigned short* dst = (blockIdx.x < 64) ? dstA : dstB;
    int tx = bid % 8, ty = bid / 8;
    int lane = threadIdx.x & 63, grp = threadIdx.x >> 6;
    for (int r = grp * 16; r < grp * 16 + 16; ++r)
        tile[r][lane] = (unsigned short)src[(ty * 64 + r) * NC + tx * 64 + lane];
    __syncthreads();
    for (int r = grp * 16; r < grp * 16 + 16; ++r)
        dst[(tx * 64 + r) * NC + ty * 64 + lane] = tile[lane][r];
}

// ===========================================================================
// Stage 1: discretize -> u16 symbols (verified R1/R5/R6).
// ===========================================================================
__global__ __launch_bounds__(256) void k_discretize(
    const float* __restrict__ x, const float* __restrict__ cent,
    unsigned short* __restrict__ out)
{
    __shared__ float c[NC];
    int tid = threadIdx.x;
    for (int i = tid; i < NC; i += 256) c[i] = cent[i];
    __syncthreads();
    int id = blockIdx.x * 256 + tid;   // 131072 exact
    float px = x[id];
    float best = fabsf(px - c[0]);
    int bi = 0;
    for (int k = 1; k < NC; ++k) {
        float d = fabsf(px - c[k]);
        if (d < best) { best = d; bi = k; }
    }
    out[id] = (unsigned short)bi;
}

// ===========================================================================
// Per-chain nibble-bin pop-min scanner, SoA columns, element stride = total
// chain columns per block (STRIDE). Logic verified R4 prev session;
// incremental masks R2; SoA R4/R6 this session. Per block: bins[word][col],
// word 0..63 nibble counts (8 bins/word), 64..79 per-window masks.
// Redundant sub-lanes of one chain run identical state; LDS reads broadcast;
// far-insert plain RMW from r lanes writes same value (verified). Window
// loaded exactly once (chunk monotone) => stored mask exact. Pop budget
// exact => ensure() bounded.
// ===========================================================================
template<int STRIDE>
struct ScanL {
    uint32_t* col;     // bins + colidx; element stride STRIDE words
    uint64_t w0, w1;   // current 32-bin window (128b of nibble counts)
    uint32_t mask;     // bit k <=> bin (chunk*32+k) nonzero
    int chunk;

    __device__ inline void init(uint32_t* c) { col = c; mask = 0; chunk = -1; }
    __device__ inline void load() {
        uint32_t a0 = col[(chunk * 4 + 0) * STRIDE];
        uint32_t a1 = col[(chunk * 4 + 1) * STRIDE];
        uint32_t a2 = col[(chunk * 4 + 2) * STRIDE];
        uint32_t a3 = col[(chunk * 4 + 3) * STRIDE];
        mask = col[(64 + chunk) * STRIDE];      // precomputed window mask
        w0 = ((uint64_t)a1 << 32) | a0;
        w1 = ((uint64_t)a3 << 32) | a2;
    }
    __device__ inline void ensure() { while (mask == 0) { ++chunk; load(); } }
    __device__ inline int  peek()   { ensure(); return chunk * 32 + (int)__builtin_ctz(mask); }
    __device__ inline void consume_min() {          // precondition: mask != 0
        int k = (int)__builtin_ctz(mask);
        int sh = (k & 15) << 2;
        bool hi = k >= 16;
        uint64_t cw = hi ? w1 : w0;
        uint32_t cnt = (uint32_t)(cw >> sh) & 0xFu;
        cw -= (1ull << sh);
        if (hi) w1 = cw; else w0 = cw;
        if (cnt == 1) mask &= ~(1u << k);
    }
    __device__ inline int pop() { int v = peek(); consume_min(); return v; }
    __device__ inline void insert(int v) {          // precondition: v >= chunk*32
        int rel = v - chunk * 32;
        if (rel < 32) {
            int sh = (rel & 15) << 2;
            bool hi = rel >= 16;
            uint64_t cw = hi ? w1 : w0;
            cw += (1ull << sh);
            if (hi) w1 = cw; else w0 = cw;
            mask |= (1u << rel);
        } else {
            // redundant sub-lanes: same old, same new => plain RMW safe
            col[(v >> 3) * STRIDE] += (1u << ((v & 7) << 2));
            col[(64 + (v >> 5)) * STRIDE] |= (1u << (v & 31));
        }
    }
};

// ===========================================================================
// Symbolic conv, single chain per thread-slot (R6 structure) — used by conv1.
// ===========================================================================
template<typename IT, typename OT, bool KMAJOR, int INST,
         int CIN, int CO, int IH, int IW, int OH, int OW>
__device__ __forceinline__ void conv_body1(
    const IT* __restrict__ in_sym, const int* __restrict__ wsym,
    const unsigned short* __restrict__ convT, const int* __restrict__ add_lut,
    const int* __restrict__ bias_lut, const int* __restrict__ relu_lut,
    OT* __restrict__ out)
{
    constexpr int N    = 25 * CIN;
    constexpr int SUB  = 64 / INST;
    constexpr int PPI  = OH * OW;
    constexpr int BPC  = (128 * PPI) / INST;
    __shared__ uint32_t bins[80 * INST];
    int tid = threadIdx.x;
    int il  = tid % INST;
    int sub = tid / INST;

    for (int i = tid; i < 80 * INST; i += 64) bins[i] = 0u;

    int posg = blockIdx.x % BPC;
    int co   = blockIdx.x / BPC;
    int pos  = posg * INST + il;
    int b  = pos / PPI;
    int yx = pos % PPI;
    int oy = yx / OW, ox = yx % OW;
    __syncthreads();

#pragma unroll 4
    for (int n = sub; n < N; n += SUB) {
        int i   = n / (5 * CIN);
        int rem = n % (5 * CIN);
        int j   = rem / CIN;
        int c   = rem % CIN;
        int s = (int)in_sym[((b * IH + (oy * 2 + i)) * IW + (ox * 2 + j)) * CIN + c];
        int w = wsym[n * CO + co];
        int g = convT[w * NC + s];
        atomicAdd(&bins[(g >> 3) * INST + il], 1u << ((g & 7) << 2));
        atomicOr (&bins[(64 + (g >> 5)) * INST + il], 1u << (g & 31));
    }
    __syncthreads();

    ScanL<INST> sc; sc.init(bins + il);
    int t = sc.pop();
    int u = sc.pop();
    int v = sc.pop();
    int t2 = add_lut[u * NC + t];
#pragma unroll 1
    for (int j = 1; j <= N - 3; ++j) {
        int bb = sc.pop();
        bool cA = (t2 <= v);
        bool cC = (t2 > bb);
        t = cA ? t2 : v;
        u = cA ? v : (cC ? bb : t2);
        int t2n = add_lut[u * NC + t];
        __builtin_amdgcn_sched_barrier(0);
        if (cC) { sc.insert(t2); v = sc.pop(); }
        else    v = bb;
        t2 = t2n;
    }
    t = t2;
    t = add_lut[v * NC + t];
    if (sub == 0) {
        int r = relu_lut[bias_lut[t * CO + co]];
        if (KMAJOR) out[(co * PPI + yx) * 128 + b] = (OT)r;
        else        out[pos * CO + co] = (OT)r;
    }
}

// ===========================================================================
// Symbolic conv, TWO independent chains per thread (R7): depth-2 ILP across
// chains hides per-link wait (load flight + LDS in-order latency) that a
// single chain cannot. INST=16, r=4 kept => per-link issue unchanged vs R6;
// 32 chains/block, 1600 blocks. Fold logic bit-identical per chain.
// ===========================================================================
template<typename IT, typename OT, bool KMAJOR, int INST,
         int CIN, int CO, int IH, int IW, int OH, int OW>
__device__ __forceinline__ void conv_body2(
    const IT* __restrict__ in_sym, const int* __restrict__ wsym,
    const unsigned short* __restrict__ convT, const int* __restrict__ add_lut,
    const int* __restrict__ bias_lut, const int* __restrict__ relu_lut,
    OT* __restrict__ out)
{
    constexpr int N    = 25 * CIN;
    constexpr int SUB  = 64 / INST;
    constexpr int PPI  = OH * OW;
    constexpr int CH   = 2 * INST;              // chains per block
    constexpr int BPC  = (128 * PPI) / CH;      // exact
    __shared__ uint32_t bins[80 * CH];
    int tid = threadIdx.x;
    int il  = tid % INST;
    int sub = tid / INST;

    for (int i = tid; i < 80 * CH; i += 64) bins[i] = 0u;

    int posg = blockIdx.x % BPC;
    int co   = blockIdx.x / BPC;
    int posA = posg * CH + il;
    int posB = posg * CH + INST + il;
    int bA = posA / PPI, yxA = posA % PPI, oyA = yxA / OW, oxA = yxA % OW;
    int bB = posB / PPI, yxB = posB % PPI, oyB = yxB / OW, oxB = yxB % OW;
    __syncthreads();

#pragma unroll 2
    for (int n = sub; n < N; n += SUB) {        // build both chains
        int i   = n / (5 * CIN);
        int rem = n % (5 * CIN);
        int j   = rem / CIN;
        int c   = rem % CIN;
        int w = wsym[n * CO + co];
        int sA = (int)in_sym[((bA * IH + (oyA * 2 + i)) * IW + (oxA * 2 + j)) * CIN + c];
        int gA = convT[w * NC + sA];
        atomicAdd(&bins[(gA >> 3) * CH + il], 1u << ((gA & 7) << 2));
        atomicOr (&bins[(64 + (gA >> 5)) * CH + il], 1u << (gA & 31));
        int sB = (int)in_sym[((bB * IH + (oyB * 2 + i)) * IW + (oxB * 2 + j)) * CIN + c];
        int gB = convT[w * NC + sB];
        atomicAdd(&bins[(gB >> 3) * CH + INST + il], 1u << ((gB & 7) << 2));
        atomicOr (&bins[(64 + (gB >> 5)) * CH + INST + il], 1u << (gB & 31));
    }
    __syncthreads();

    ScanL<CH> scA; scA.init(bins + il);
    ScanL<CH> scB; scB.init(bins + INST + il);
    int tA = scA.pop(), uA = scA.pop(), vA = scA.pop();
    int t2A = add_lut[uA * NC + tA];
    int tB = scB.pop(), uB = scB.pop(), vB = scB.pop();
    int t2B = add_lut[uB * NC + tB];
#pragma unroll 1
    for (int j = 1; j <= N - 3; ++j) {
        // --- chain A link (B's load in flight below/above) ---
        int bbA = scA.pop();
        bool cAA = (t2A <= vA), cCA = (t2A > bbA);
        tA = cAA ? t2A : vA;
        uA = cAA ? vA : (cCA ? bbA : t2A);
        int t2nA = add_lut[uA * NC + tA];
        __builtin_amdgcn_sched_barrier(0);
        if (cCA) { scA.insert(t2A); vA = scA.pop(); }
        else     vA = bbA;
        t2A = t2nA;
        // --- chain B link ---
        int bbB = scB.pop();
        bool cAB = (t2B <= vB), cCB = (t2B > bbB);
        tB = cAB ? t2B : vB;
        uB = cAB ? vB : (cCB ? bbB : t2B);
        int t2nB = add_lut[uB * NC + tB];
        __builtin_amdgcn_sched_barrier(0);
        if (cCB) { scB.insert(t2B); vB = scB.pop(); }
        else     vB = bbB;
        t2B = t2nB;
    }
    tA = t2A; tA = add_lut[vA * NC + tA];
    tB = t2B; tB = add_lut[vB * NC + tB];
    if (sub == 0) {
        int rA = relu_lut[bias_lut[tA * CO + co]];
        int rB = relu_lut[bias_lut[tB * CO + co]];
        if (KMAJOR) {
            out[(co * PPI + yxA) * 128 + bA] = (OT)rA;
            out[(co * PPI + yxB) * 128 + bB] = (OT)rB;
        } else {
            out[posA * CO + co] = (OT)rA;
            out[posB * CO + co] = (OT)rB;
        }
    }
}

__global__ __launch_bounds__(64) void k_conv1(
    const unsigned short* in, const int* wsym, const unsigned short* convT,
    const int* add_lut, const int* bias, const int* relu, unsigned short* out)
{
    conv_body1<unsigned short, unsigned short, false, 64, 1, 6, 32, 32, 14, 14>(
        in, wsym, convT, add_lut, bias, relu, out);
}

__global__ __launch_bounds__(64) void k_conv2(
    const unsigned short* in, const int* wsym, const unsigned short* convT,
    const int* add_lut, const int* bias, const int* relu, int* out)
{
    conv_body2<unsigned short, int, true, 16, 6, 16, 14, 14, 5, 5>(
        in, wsym, convT, add_lut, bias, relu, out);
}

// ===========================================================================
// Symbolic FC, _fc_reduce = ascending pops (verified R1/R2). R7: TWO chains
// per thread (ILP-2), INST=8, r=8, 16 chains/block. Fold is pure latency
// chain (confirmed R6) => depth-2 should ~halve. fc1: 960, fc2: 672 blocks.
// ===========================================================================
template<int M, int K>
__device__ __forceinline__ void fc_body(
    const int* __restrict__ in_sym,    // (K, 128) k-major
    const int* __restrict__ wsym,      // (M, K)
    const unsigned short* __restrict__ fcT,  // (NC, NC) [w][x]
    const int* __restrict__ add_lut,   // (NC, NC)
    const int* __restrict__ bias_lut,  // (NC, M)
    const int* __restrict__ relu_lut,  // (NC,)
    int* __restrict__ out)             // (M, 128) m-major
{
    constexpr int INST = 8;
    constexpr int CH   = 16;
    constexpr int SUB  = 8;
    __shared__ uint32_t bins[80 * CH];
    int tid = threadIdx.x;
    int il  = tid % INST;
    int sub = tid / INST;

    for (int i = tid; i < 80 * CH; i += 64) bins[i] = 0u;

    int m  = blockIdx.x / 8;                   // block-uniform
    int bg = blockIdx.x % 8;
    int bA = bg * CH + il;
    int bB = bg * CH + INST + il;
    __syncthreads();

#pragma unroll 2
    for (int k = sub; k < K; k += SUB) {
        int w = wsym[m * K + k];
        int xA = in_sym[k * 128 + bA];
        int gA = fcT[w * NC + xA];
        atomicAdd(&bins[(gA >> 3) * CH + il], 1u << ((gA & 7) << 2));
        atomicOr (&bins[(64 + (gA >> 5)) * CH + il], 1u << (gA & 31));
        int xB = in_sym[k * 128 + bB];
        int gB = fcT[w * NC + xB];
        atomicAdd(&bins[(gB >> 3) * CH + INST + il], 1u << ((gB & 7) << 2));
        atomicOr (&bins[(64 + (gB >> 5)) * CH + INST + il], 1u << (gB & 31));
    }
    __syncthreads();

    ScanL<CH> scA; scA.init(bins + il);
    ScanL<CH> scB; scB.init(bins + INST + il);
    int tA = scA.pop();
    int xA = scA.pop();
    int t2A = add_lut[xA * NC + tA];
    int tB = scB.pop();
    int xB = scB.pop();
    int t2B = add_lut[xB * NC + tB];
#pragma unroll 1
    for (int s = 1; s < K - 1; ++s) {
        int xnA = scA.pop();                   // overlaps in-flight loads
        tA = t2A;
        t2A = add_lut[xnA * NC + tA];
        __builtin_amdgcn_sched_barrier(0);
        int xnB = scB.pop();
        tB = t2B;
        t2B = add_lut[xnB * NC + tB];
        __builtin_amdgcn_sched_barrier(0);
    }
    tA = t2A; tB = t2B;
    if (sub == 0) {
        out[m * 128 + bA] = relu_lut[bias_lut[tA * M + m]];
        out[m * 128 + bB] = relu_lut[bias_lut[tB * M + m]];
    }
}

__global__ __launch_bounds__(64) void k_fc1(
    const int* in, const int* wsym, const unsigned short* fcT,
    const int* add_lut, const int* bias, const int* relu, int* out)
{
    fc_body<120, 400>(in, wsym, fcT, add_lut, bias, relu, out);
}

__global__ __launch_bounds__(64) void k_fc2(
    const int* in, const int* wsym, const unsigned short* fcT,
    const int* add_lut, const int* bias, const int* relu, int* out)
{
    fc_body<84, 120>(in, wsym, fcT, add_lut, bias, relu, out);
}

// ===========================================================================
// Head: feats = centroid[sym], logits @ W^T + b, softmax. Reads m-major f2.
// ===========================================================================
__global__ __launch_bounds__(64) void k_head(
    const int* __restrict__ f2m,       // (84, 128) m-major
    const float* __restrict__ cent,    // (NC,)
    const float* __restrict__ w,       // (10, 84)
    const float* __restrict__ bias,    // (10,)
    float* __restrict__ out)           // (128, 10)
{
    int b = blockIdx.x * 64 + threadIdx.x;
    float acc[10];
#pragma unroll
    for (int o = 0; o < 10; ++o) acc[o] = bias[o];
    for (int k = 0; k < 84; ++k) {
        float f = cent[f2m[k * 128 + b]];      // coalesced
#pragma unroll
        for (int o = 0; o < 10; ++o) acc[o] += f * w[o * 84 + k];
    }
    float mx = acc[0];
#pragma unroll
    for (int o = 1; o < 10; ++o) mx = fmaxf(mx, acc[o]);
    float s = 0.f;
#pragma unroll
    for (int o = 0; o < 10; ++o) { acc[o] = expf(acc[o] - mx); s += acc[o]; }
    float inv = 1.f / s;
#pragma unroll
    for (int o = 0; o < 10; ++o) out[b * 10 + o] = acc[o] * inv;
}

// ===========================================================================
extern "C" void kernel_launch(void* const* d_in, const int* in_sizes, int n_in,
                              void* d_out, int out_size, void* d_ws, size_t ws_size,
                              hipStream_t stream)
{
    const float* x_bat  = (const float*)d_in[0];
    const float* cent   = (const float*)d_in[1];
    const int* conv_lut = (const int*)d_in[2];
    const int* fc_lut   = (const int*)d_in[3];
    const int* add_lut  = (const int*)d_in[4];
    const int* relu_lut = (const int*)d_in[5];
    const int* c1_bias  = (const int*)d_in[6];
    const int* c2_bias  = (const int*)d_in[7];
    const int* f1_bias  = (const int*)d_in[8];
    const int* f2_bias  = (const int*)d_in[9];
    const int* c1f      = (const int*)d_in[10];
    const int* c2f      = (const int*)d_in[11];
    const int* f1f      = (const int*)d_in[12];
    const int* f2f      = (const int*)d_in[13];
    const float* fc3_w  = (const float*)d_in[14];
    const float* fc3_b  = (const float*)d_in[15];
    float* out = (float*)d_out;

    char* ws = (char*)d_ws;
    unsigned short* convT = (unsigned short*)(ws);            // 512 KB
    unsigned short* fcT   = (unsigned short*)(ws + 524288);   // 512 KB
    unsigned short* sym0  = (unsigned short*)(ws + 1048576);  // 256 KB
    unsigned short* c1o   = (unsigned short*)(ws + 1310720);  // 294 KB (b,14,14,6) u16
    int* c2o = (int*)(ws + 1611776);                          // 200 KB (400,128) k-major
    int* f1o = (int*)(ws + 1816576);                          //  60 KB (120,128) m-major
    int* f2o = (int*)(ws + 1878016);                          //  42 KB (84,128)  m-major
    // peak ws ~1.92 MB

    k_transpose_pack2<<<128, 256, 0, stream>>>(conv_lut, convT, fc_lut, fcT);
    k_discretize<<<512, 256, 0, stream>>>(x_bat, cent, sym0);
    // conv1: 6 co x 392 pos-groups = 2352 blocks (64 chains, r=1)
    k_conv1<<<2352, 64, 0, stream>>>(sym0, c1f, convT, add_lut, c1_bias, relu_lut, c1o);
    // conv2: 16 co x 100 pos-groups = 1600 blocks (32 chains, r=4, ILP-2)
    k_conv2<<<1600, 64, 0, stream>>>(c1o, c2f, convT, add_lut, c2_bias, relu_lut, c2o);
    // fc1: 120 m x 8 b-groups = 960 blocks (16 chains, r=8, ILP-2)
    k_fc1<<<960, 64, 0, stream>>>(c2o, f1f, fcT, add_lut, f1_bias, relu_lut, f1o);
    // fc2: 84 m x 8 b-groups = 672 blocks
    k_fc2<<<672, 64, 0, stream>>>(f1o, f2f, fcT, add_lut, f2_bias, relu_lut, f2o);
    k_head<<<2, 64, 0, stream>>>(f2o, cent, fc3_w, fc3_b, out);
}